// Round 2
// baseline (56.911 us; speedup 1.0000x reference)
//
#include <hip/hip_runtime.h>

#define NCLS   80
#define NA     9
#define NH     64
#define NW     64
#define NB     8
#define NGT    32
#define NANCH  (NA * NH * NW)        // 36864 anchors per image
#define BLK_A  128                   // anchors per block
#define BLKS_PER_IMG (NANCH / BLK_A) // 288
#define NTHR   256
#define F4_PER_BLOCK (BLK_A * NCLS / 4)  // 2560
#define K_ITERS (F4_PER_BLOCK / NTHR)    // 10

// Anchor W/H computed in double (matches Python float arithmetic), cast to f32.
__device__ __constant__ float c_aw[9] = {
    (float)(32.0 * 1.0    * 1.0), (float)(32.0 * 1.0    * 1.4), (float)(32.0 * 1.0    * 0.7),
    (float)(32.0 * 1.2599 * 1.0), (float)(32.0 * 1.2599 * 1.4), (float)(32.0 * 1.2599 * 0.7),
    (float)(32.0 * 1.5874 * 1.0), (float)(32.0 * 1.5874 * 1.4), (float)(32.0 * 1.5874 * 0.7)};
__device__ __constant__ float c_ah[9] = {
    (float)(32.0 * 1.0    * 1.0), (float)(32.0 * 1.0    * 0.7), (float)(32.0 * 1.0    * 1.4),
    (float)(32.0 * 1.2599 * 1.0), (float)(32.0 * 1.2599 * 0.7), (float)(32.0 * 1.2599 * 1.4),
    (float)(32.0 * 1.5874 * 1.0), (float)(32.0 * 1.5874 * 0.7), (float)(32.0 * 1.5874 * 1.4)};

// ws float layout: acc[0] = loss_xywh ; acc[1+b] = im_loss_cls[b] ; acc[16+b] = num_pos[b]
#define ACC_FLOATS 32

__global__ __launch_bounds__(NTHR) void retina_main(
    const float* __restrict__ t_xywh,      // [B, N, 4]
    const float* __restrict__ cls_logits,  // [B, N, 80]
    const float* __restrict__ gt_bboxes,   // [B, 32, 4] cxcywh
    const int*   __restrict__ gt_cats,     // [B, 32]
    float* __restrict__ acc)
{
    __shared__ float4 s_gt[NGT];
    __shared__ int    s_cat[NGT];
    __shared__ int    s_flag[BLK_A];   // -1: skip; 0..79: pos class; 256: neg-only
    __shared__ float  s_red[4 * 3];

    const int tid  = threadIdx.x;
    const int blk  = blockIdx.x;
    const int b    = blk / BLKS_PER_IMG;           // image index (block never spans images)
    const int ablk = blk % BLKS_PER_IMG;

    if (tid < NGT) {
        s_gt[tid]  = ((const float4*)gt_bboxes)[b * NGT + tid];
        s_cat[tid] = gt_cats[b * NGT + tid];
    }
    __syncthreads();

    float lx = 0.0f, pcnt = 0.0f;
    if (tid < BLK_A) {
        const int n = ablk * BLK_A + tid;          // anchor index within image
        // ---- anchor geometry ----
        const int a  = n >> 12;                    // n / (64*64)
        const int hy = (n >> 6) & 63;
        const int wx = n & 63;
        const float acx = (wx + 0.5f) * 8.0f;
        const float acy = (hy + 0.5f) * 8.0f;
        const float aw  = c_aw[a];
        const float ah  = c_ah[a];

        // ---- IoU vs 32 GTs, bit-exact op order vs numpy reference ----
        float best = -1.0f;
        int   bi   = 0;
        {
#pragma clang fp contract(off)
            const float a_tlx = acx - aw * 0.5f, a_tly = acy - ah * 0.5f;
            const float a_brx = acx + aw * 0.5f, a_bry = acy + ah * 0.5f;
            const float area_a = aw * ah;
            for (int g = 0; g < NGT; ++g) {
                const float4 gb = s_gt[g];
                const float g_tlx = gb.x - gb.z * 0.5f, g_tly = gb.y - gb.w * 0.5f;
                const float g_brx = gb.x + gb.z * 0.5f, g_bry = gb.y + gb.w * 0.5f;
                float dx = fminf(a_brx, g_brx) - fmaxf(a_tlx, g_tlx);
                float dy = fminf(a_bry, g_bry) - fmaxf(a_tly, g_tly);
                dx = fmaxf(dx, 0.0f);
                dy = fmaxf(dy, 0.0f);
                const float inter = dx * dy;
                const float area_g = gb.z * gb.w;
                const float uni  = area_a + area_g - inter;   // no fma
                const float iou  = inter / uni;
                if (iou > best) { best = iou; bi = g; }       // strict > = first argmax
            }
        }

        const bool pos = best > 0.5f;
        const bool neg = best < 0.4f;
        s_flag[tid] = (pos | neg) ? (pos ? s_cat[bi] : 256) : -1;

        // ---- xywh regression loss (positives only) ----
        if (pos) {
            pcnt = 1.0f;
            const float4 g = s_gt[bi];
            const float4 t = ((const float4*)t_xywh)[(size_t)b * NANCH + n];
            const float tx = (g.x - acx) / aw;
            const float ty = (g.y - acy) / ah;
            const float tw = logf(g.z / aw + 1e-8f);
            const float th = logf(g.w / ah + 1e-8f);
            const float d0 = t.x - tx, d1 = t.y - ty, d2 = t.z - tw, d3 = t.w - th;
            lx = d0 * d0 + d1 * d1 + d2 * d2 + d3 * d3;
        }
    }
    __syncthreads();

    // ---- class BCE over this block's 128 anchors x 80 classes (40 KB, coalesced f4) ----
    float lc = 0.0f;
    const float4* base = (const float4*)cls_logits + (size_t)blk * F4_PER_BLOCK;
#pragma unroll
    for (int k = 0; k < K_ITERS; ++k) {
        const int e  = k * NTHR + tid;       // float4 index within block chunk
        const int la = e / 20;               // local anchor (20 f4 per anchor)
        const int c0 = (e - la * 20) * 4;    // starting class of this f4
        const float4 x = base[e];
        const int f = s_flag[la];
        if (f >= 0) {
            const float xs[4] = {x.x, x.y, x.z, x.w};
#pragma unroll
            for (int j = 0; j < 4; ++j) {
                const float xv = xs[j];
                float sp = fmaxf(xv, 0.0f) + __logf(1.0f + __expf(-fabsf(xv)));
                if (c0 + j == f) sp -= xv;   // one-hot target at positive anchor
                lc += sp;
            }
        }
    }

    // ---- block reduction of (lc, lx, pcnt) ----
    float v0 = lc, v1 = lx, v2 = pcnt;
    for (int o = 32; o > 0; o >>= 1) {
        v0 += __shfl_down(v0, o);
        v1 += __shfl_down(v1, o);
        v2 += __shfl_down(v2, o);
    }
    const int wave = tid >> 6;
    if ((tid & 63) == 0) {
        s_red[wave * 3 + 0] = v0;
        s_red[wave * 3 + 1] = v1;
        s_red[wave * 3 + 2] = v2;
    }
    __syncthreads();
    if (tid == 0) {
        float c = 0.0f, xw = 0.0f, pc = 0.0f;
        for (int w2 = 0; w2 < 4; ++w2) {
            c  += s_red[w2 * 3 + 0];
            xw += s_red[w2 * 3 + 1];
            pc += s_red[w2 * 3 + 2];
        }
        atomicAdd(&acc[1 + b], c);
        if (xw != 0.0f) atomicAdd(&acc[0], xw);
        if (pc != 0.0f) atomicAdd(&acc[16 + b], pc);
    }
}

__global__ void retina_final(const float* __restrict__ acc, float* __restrict__ out)
{
    float s = 0.0f;
    for (int b = 0; b < NB; ++b)
        s += acc[1 + b] / (acc[16 + b] + 1.0f);
    out[0] = (acc[0] + s) / (float)NB;
}

extern "C" void kernel_launch(void* const* d_in, const int* in_sizes, int n_in,
                              void* d_out, int out_size, void* d_ws, size_t ws_size,
                              hipStream_t stream)
{
    const float* t_xywh     = (const float*)d_in[0];
    const float* cls_logits = (const float*)d_in[1];
    const float* gt_bboxes  = (const float*)d_in[2];
    const int*   gt_cats    = (const int*)d_in[3];

    float* acc = (float*)d_ws;
    hipMemsetAsync(d_ws, 0, ACC_FLOATS * sizeof(float), stream);

    const int grid = NB * BLKS_PER_IMG;  // 2304 blocks, one 128-anchor slice each
    retina_main<<<grid, NTHR, 0, stream>>>(t_xywh, cls_logits, gt_bboxes, gt_cats, acc);
    retina_final<<<1, 1, 0, stream>>>(acc, (float*)d_out);
}

// Round 3
// 40.425 us; speedup vs baseline: 1.4078x; 1.4078x over previous
//
#include <hip/hip_runtime.h>

#define NCLS   80
#define NA     9
#define NH     64
#define NW     64
#define NB     8
#define NGT    32
#define NANCH  (NA * NH * NW)        // 36864 anchors per image
#define BLK_A  128                   // anchors per block
#define BLKS_PER_IMG (NANCH / BLK_A) // 288
#define NTHR   256
#define NBLK   (NB * BLKS_PER_IMG)   // 2304
#define KI     10                    // float4 logit loads per thread

// ws partials layout (floats): [PLC + blk] cls loss, [PLX + blk] xywh loss, [PPC + blk] pos count
#define PLC 0
#define PLX NBLK
#define PPC (2 * NBLK)

// Anchor W/H computed in double (matches Python float arithmetic), cast to f32.
__device__ __constant__ float c_aw[9] = {
    (float)(32.0 * 1.0    * 1.0), (float)(32.0 * 1.0    * 1.4), (float)(32.0 * 1.0    * 0.7),
    (float)(32.0 * 1.2599 * 1.0), (float)(32.0 * 1.2599 * 1.4), (float)(32.0 * 1.2599 * 0.7),
    (float)(32.0 * 1.5874 * 1.0), (float)(32.0 * 1.5874 * 1.4), (float)(32.0 * 1.5874 * 0.7)};
__device__ __constant__ float c_ah[9] = {
    (float)(32.0 * 1.0    * 1.0), (float)(32.0 * 1.0    * 0.7), (float)(32.0 * 1.0    * 1.4),
    (float)(32.0 * 1.2599 * 1.0), (float)(32.0 * 1.2599 * 0.7), (float)(32.0 * 1.2599 * 1.4),
    (float)(32.0 * 1.5874 * 1.0), (float)(32.0 * 1.5874 * 0.7), (float)(32.0 * 1.5874 * 1.4)};

__global__ __launch_bounds__(NTHR) void retina_main(
    const float* __restrict__ t_xywh,      // [B, N, 4]
    const float* __restrict__ cls_logits,  // [B, N, 80]
    const float* __restrict__ gt_bboxes,   // [B, 32, 4] cxcywh
    const int*   __restrict__ gt_cats,     // [B, 32]
    float* __restrict__ part)
{
    __shared__ float4 s_gt[NGT];
    __shared__ int    s_cat[NGT];
    __shared__ int    s_flag[BLK_A];   // -1: skip; 0..79: pos class; 256: neg-only
    __shared__ float  s_red[4 * 3];

    const int tid  = threadIdx.x;
    const int blk  = blockIdx.x;
    const int b    = blk / BLKS_PER_IMG;           // image index (block never spans images)
    const int ablk = blk % BLKS_PER_IMG;

    // ---- issue ALL logit loads up front; IoU phase below hides their latency ----
    const float4* base = (const float4*)cls_logits + (size_t)blk * (BLK_A * NCLS / 4);
    float4 xb[KI];
#pragma unroll
    for (int k = 0; k < KI; ++k) xb[k] = base[k * NTHR + tid];

    if (tid < NGT) {
        s_gt[tid]  = ((const float4*)gt_bboxes)[b * NGT + tid];
        s_cat[tid] = gt_cats[b * NGT + tid];
    }
    __syncthreads();

    float lx = 0.0f, pcnt = 0.0f;
    if (tid < BLK_A) {
        const int n = ablk * BLK_A + tid;          // anchor index within image
        const int a  = n >> 12;                    // n / (64*64)
        const int hy = (n >> 6) & 63;
        const int wx = n & 63;
        const float acx = (wx + 0.5f) * 8.0f;
        const float acy = (hy + 0.5f) * 8.0f;
        const float aw  = c_aw[a];
        const float ah  = c_ah[a];

        // ---- IoU vs 32 GTs, bit-exact op order vs numpy reference ----
        float best = -1.0f;
        int   bi   = 0;
        {
#pragma clang fp contract(off)
            const float a_tlx = acx - aw * 0.5f, a_tly = acy - ah * 0.5f;
            const float a_brx = acx + aw * 0.5f, a_bry = acy + ah * 0.5f;
            const float area_a = aw * ah;
            for (int g = 0; g < NGT; ++g) {
                const float4 gb = s_gt[g];
                const float g_tlx = gb.x - gb.z * 0.5f, g_tly = gb.y - gb.w * 0.5f;
                const float g_brx = gb.x + gb.z * 0.5f, g_bry = gb.y + gb.w * 0.5f;
                float dx = fminf(a_brx, g_brx) - fmaxf(a_tlx, g_tlx);
                float dy = fminf(a_bry, g_bry) - fmaxf(a_tly, g_tly);
                dx = fmaxf(dx, 0.0f);
                dy = fmaxf(dy, 0.0f);
                const float inter = dx * dy;
                const float area_g = gb.z * gb.w;
                const float uni  = area_a + area_g - inter;   // no fma
                const float iou  = inter / uni;
                if (iou > best) { best = iou; bi = g; }       // strict > = first argmax
            }
        }

        const bool pos = best > 0.5f;
        const bool neg = best < 0.4f;
        s_flag[tid] = (pos | neg) ? (pos ? s_cat[bi] : 256) : -1;

        if (pos) {
            pcnt = 1.0f;
            const float4 g = s_gt[bi];
            const float4 t = ((const float4*)t_xywh)[(size_t)b * NANCH + n];
            const float tx = (g.x - acx) / aw;
            const float ty = (g.y - acy) / ah;
            const float tw = logf(g.z / aw + 1e-8f);
            const float th = logf(g.w / ah + 1e-8f);
            const float d0 = t.x - tx, d1 = t.y - ty, d2 = t.z - tw, d3 = t.w - th;
            lx = d0 * d0 + d1 * d1 + d2 * d2 + d3 * d3;
        }
    }
    __syncthreads();

    // ---- class BCE from prefetched registers (flags from LDS) ----
    float lc = 0.0f;
#pragma unroll
    for (int k = 0; k < KI; ++k) {
        const int e  = k * NTHR + tid;       // float4 index within block chunk
        const int la = e / 20;               // local anchor (20 f4 per anchor)
        const int c0 = (e - la * 20) * 4;    // starting class of this f4
        const float4 x = xb[k];
        const int f = s_flag[la];
        if (f >= 0) {
            const float xs[4] = {x.x, x.y, x.z, x.w};
#pragma unroll
            for (int j = 0; j < 4; ++j) {
                const float xv = xs[j];
                float sp = fmaxf(xv, 0.0f) + __logf(1.0f + __expf(-fabsf(xv)));
                if (c0 + j == f) sp -= xv;   // one-hot target at positive anchor
                lc += sp;
            }
        }
    }

    // ---- block reduction of (lc, lx, pcnt) ----
    float v0 = lc, v1 = lx, v2 = pcnt;
    for (int o = 32; o > 0; o >>= 1) {
        v0 += __shfl_down(v0, o);
        v1 += __shfl_down(v1, o);
        v2 += __shfl_down(v2, o);
    }
    const int wave = tid >> 6;
    if ((tid & 63) == 0) {
        s_red[wave * 3 + 0] = v0;
        s_red[wave * 3 + 1] = v1;
        s_red[wave * 3 + 2] = v2;
    }
    __syncthreads();
    if (tid == 0) {
        float c = 0.0f, xw = 0.0f, pc = 0.0f;
        for (int w2 = 0; w2 < 4; ++w2) {
            c  += s_red[w2 * 3 + 0];
            xw += s_red[w2 * 3 + 1];
            pc += s_red[w2 * 3 + 2];
        }
        part[PLC + blk] = c;    // unconditional -> no ws memset needed
        part[PLX + blk] = xw;
        part[PPC + blk] = pc;
    }
}

__global__ __launch_bounds__(256) void retina_final(
    const float* __restrict__ part, float* __restrict__ out)
{
    __shared__ float s_lc[NB], s_pc[NB], s_lx[4];
    const int tid = threadIdx.x;

    // per-image cls / pos sums: 32 lanes per image (lanes stay inside one 32-group)
    const int b = tid >> 5, l = tid & 31;
    float lc = 0.0f, pc = 0.0f;
    for (int i = l; i < BLKS_PER_IMG; i += 32) {
        lc += part[PLC + b * BLKS_PER_IMG + i];
        pc += part[PPC + b * BLKS_PER_IMG + i];
    }
    for (int o = 16; o > 0; o >>= 1) {        // xor butterfly never crosses the 32-group
        lc += __shfl_xor(lc, o);
        pc += __shfl_xor(pc, o);
    }
    if (l == 0) { s_lc[b] = lc; s_pc[b] = pc; }

    // global xywh sum
    float lxs = 0.0f;
    for (int i = tid; i < NBLK; i += 256) lxs += part[PLX + i];
    for (int o = 32; o > 0; o >>= 1) lxs += __shfl_down(lxs, o);
    if ((tid & 63) == 0) s_lx[tid >> 6] = lxs;
    __syncthreads();

    if (tid == 0) {
        const float lxt = s_lx[0] + s_lx[1] + s_lx[2] + s_lx[3];
        float s = 0.0f;
        for (int bb = 0; bb < NB; ++bb)
            s += s_lc[bb] / (s_pc[bb] + 1.0f);
        out[0] = (lxt + s) / (float)NB;
    }
}

extern "C" void kernel_launch(void* const* d_in, const int* in_sizes, int n_in,
                              void* d_out, int out_size, void* d_ws, size_t ws_size,
                              hipStream_t stream)
{
    const float* t_xywh     = (const float*)d_in[0];
    const float* cls_logits = (const float*)d_in[1];
    const float* gt_bboxes  = (const float*)d_in[2];
    const int*   gt_cats    = (const int*)d_in[3];

    float* part = (float*)d_ws;   // 3 * 2304 floats = 27.6 KB

    retina_main<<<NBLK, NTHR, 0, stream>>>(t_xywh, cls_logits, gt_bboxes, gt_cats, part);
    retina_final<<<1, 256, 0, stream>>>(part, (float*)d_out);
}